// Round 2
// baseline (749.612 us; speedup 1.0000x reference)
//
#include <hip/hip_runtime.h>
#include <math.h>

// PNANet on MI355X, round 2: fix FMA4 macro param/member-name collision.
//
// Key algebraic restructurings vs the reference:
//  * pre-MLP factorized: m[n,e] = u[n] + v[nbr[n,e]] with u = x@W_pre[:, :F] + b,
//    v = x@W_pre[:, F:].  min/max/mean(u+v_e) = u + min/max/mean(v_e); std(u+v_e)=std(v_e).
//  * degree == 7 for all nodes -> amp is a constant; scalers folded into
//    W_eff = W_identity + amp*W_amp + (1/amp)*W_atten  (post-MLP K: 832->320, 104->40).

#define NGRAPH 128
#define NPG    512
#define NN     (NGRAPH*NPG)   // 65536
#define KNB    7

constexpr double AVG_DEG_LOG_D = 2.0239670479173344;  // (100*ln6+200*ln7+700*ln8)/1000
constexpr double LOG8_D        = 2.0794415416798357;

#define FMA4(A_, P_, W_) { (A_).x += (P_)*(W_).x; (A_).y += (P_)*(W_).y; (A_).z += (P_)*(W_).z; (A_).w += (P_)*(W_).w; }

// ---------------------------------------------------------------- weight prep
__global__ __launch_bounds__(256) void prep_kernel(
    const float* __restrict__ Wpost1, const float* __restrict__ Wpost2,
    const float* __restrict__ Wpre2,
    float* __restrict__ Weff1, float* __restrict__ Weff2,
    float* __restrict__ W2u, float* __restrict__ W2v)
{
    const float AMP = (float)(LOG8_D / AVG_DEG_LOG_D);
    const float ATT = (float)(AVG_DEG_LOG_D / LOG8_D);
    for (int i = blockIdx.x*256 + threadIdx.x; i < 76288; i += gridDim.x*256) {
        if (i < 2560) {
            // Weff1 [4][40][16]; g<8 = x part, g>=8 = agg part (mean,min,max,std x8)
            int t = i / 640, r = i % 640, g = r >> 4, fo = r & 15;
            float val;
            if (g < 8) val = Wpost1[(t*104 + g)*16 + fo];
            else {
                int g2 = g - 8;
                val = Wpost1[(t*104 +  8 + g2)*16 + fo]
                    + AMP*Wpost1[(t*104 + 40 + g2)*16 + fo]
                    + ATT*Wpost1[(t*104 + 72 + g2)*16 + fo];
            }
            Weff1[i] = val;
        } else if (i < 43520) {
            // Weff2 [4][320][32]; g<64 = x part, g>=64 = agg part (mean,min,max,std x64)
            int j = i - 2560;
            int t = j / 10240, r = j % 10240, g = r >> 5, fo = r & 31;
            float val;
            if (g < 64) val = Wpost2[(t*832 + g)*32 + fo];
            else {
                int g2 = g - 64;
                val = Wpost2[(t*832 +  64 + g2)*32 + fo]
                    + AMP*Wpost2[(t*832 + 320 + g2)*32 + fo]
                    + ATT*Wpost2[(t*832 + 576 + g2)*32 + fo];
            }
            Weff2[j] = val;
        } else {
            // W2u/W2v: [k=64][tf=256], tf = t*64+f ; u rows = W_pre2[t][k], v rows = W_pre2[t][64+k]
            int j = i - 43520;
            int half = j >> 14, j2 = j & 16383;
            int k = j2 >> 8, tf = j2 & 255, t = tf >> 6, f = tf & 63;
            if (half == 0) W2u[j2] = Wpre2[(t*128 +      k)*64 + f];
            else           W2v[j2] = Wpre2[(t*128 + 64 + k)*64 + f];
        }
    }
}

// ---------------------------------------------------------------- kNN (k=7) per graph
__global__ __launch_bounds__(512) void knn_kernel(const float* __restrict__ pos, int* __restrict__ nbr)
{
    __shared__ float4 posS[NPG];
    const int gb = blockIdx.x * NPG;
    {
        int j = threadIdx.x;
        posS[j] = make_float4(pos[(gb+j)*3+0], pos[(gb+j)*3+1], pos[(gb+j)*3+2], 0.f);
    }
    __syncthreads();
    const int i = threadIdx.x;
    const float4 pi = posS[i];
    float bd[KNB]; int bi[KNB];
#pragma unroll
    for (int e = 0; e < KNB; ++e) { bd[e] = 3.0e38f; bi[e] = -1; }
    for (int j = 0; j < NPG; ++j) {
        float4 pj = posS[j];
        float dx = pi.x - pj.x, dy = pi.y - pj.y, dz = pi.z - pj.z;
        float d2 = __fadd_rn(__fadd_rn(__fmul_rn(dx,dx), __fmul_rn(dy,dy)), __fmul_rn(dz,dz));
        if (j == i) d2 = __builtin_inff();          // exclude self (ref adds 1e10 on diag)
        bool cmp[KNB];
#pragma unroll
        for (int e = 0; e < KNB; ++e) cmp[e] = d2 < bd[e];   // strict < : ties keep earlier index
#pragma unroll
        for (int e = KNB-1; e >= 1; --e) {
            bd[e] = cmp[e-1] ? bd[e-1] : (cmp[e] ? d2 : bd[e]);
            bi[e] = cmp[e-1] ? bi[e-1] : (cmp[e] ? j  : bi[e]);
        }
        bd[0] = cmp[0] ? d2 : bd[0];
        bi[0] = cmp[0] ? j  : bi[0];
    }
#pragma unroll
    for (int e = 0; e < KNB; ++e) nbr[(gb+i)*KNB + e] = gb + bi[e];
}

// ---------------------------------------------------------------- layer1: u1,v1 [N,32]
__global__ __launch_bounds__(256) void a1_kernel(
    const float* __restrict__ x, const float* __restrict__ Wpre1, const float* __restrict__ bpre1,
    float* __restrict__ u1, float* __restrict__ v1)
{
    __shared__ float wS[512];
    __shared__ float bS[32];
    const int tid = threadIdx.x;
    wS[tid] = Wpre1[tid]; wS[tid+256] = Wpre1[tid+256];
    if (tid < 32) bS[tid] = bpre1[tid];
    __syncthreads();
    const int n  = blockIdx.x*8 + (tid>>5);
    const int tf = tid & 31;
    const int t = tf >> 3, f = tf & 7;
    float u = bS[tf], v = 0.f;
#pragma unroll
    for (int e = 0; e < 8; ++e) {
        float xv = x[n*8+e];
        u += xv * wS[(t*16 + e)*8 + f];
        v += xv * wS[(t*16 + 8 + e)*8 + f];
    }
    u1[n*32+tf] = u;
    v1[n*32+tf] = v;
}

// ---------------------------------------------------------------- layer1 fused: agg + post + lin -> y1 [N,64]
__global__ __launch_bounds__(256) void b1_kernel(
    const float* __restrict__ x, const int* __restrict__ nbr,
    const float* __restrict__ u1, const float* __restrict__ v1,
    const float* __restrict__ Weff1, const float* __restrict__ bpost1,
    const float* __restrict__ Wlin1, const float* __restrict__ blin1,
    float* __restrict__ y1)
{
    __shared__ int   nbrsS[16*7];
    __shared__ float xsS[16*8];
    __shared__ float aggS[16*128];   // per node: [t][mean8,min8,max8,std8]
    __shared__ float postS[16*64];
    const int tid  = threadIdx.x;
    const int base = blockIdx.x * 16;
    if (tid < 112) nbrsS[tid] = nbr[base*7 + tid];
    if (tid < 128) xsS[tid]   = x[base*8 + tid];
    __syncthreads();
#pragma unroll
    for (int it = 0; it < 2; ++it) {
        int task = tid + 256*it;
        int ln = task >> 5, tf = task & 31;
        float u = u1[(base+ln)*32 + tf];
        float s = 0.f, s2 = 0.f, mn = 3e38f, mx = -3e38f;
#pragma unroll
        for (int e = 0; e < 7; ++e) {
            float vv = v1[nbrsS[ln*7+e]*32 + tf];
            s += vv; s2 += vv*vv; mn = fminf(mn, vv); mx = fmaxf(mx, vv);
        }
        float mean = s * (1.f/7.f);
        float var  = s2 * (1.f/7.f) - mean*mean;
        float sd   = sqrtf(fmaxf(var, 0.f) + 1e-5f);
        int t = tf >> 3, f = tf & 7;
        int bo = ln*128 + t*32 + f;
        aggS[bo]    = u + mean;
        aggS[bo+8]  = u + mn;
        aggS[bo+16] = u + mx;
        aggS[bo+24] = sd;
    }
    __syncthreads();
    {   // post-MLP: 16 nodes x 64 outputs, thread = (node, 4-col group)
        int ln = tid >> 4, q = tid & 15;
        int t = q >> 2, fo4 = (q & 3) * 4;
        float4 acc = *(const float4*)&bpost1[t*16 + fo4];
#pragma unroll
        for (int g = 0; g < 8; ++g) {
            float p = xsS[ln*8+g];
            float4 wv4 = *(const float4*)&Weff1[(t*40 + g)*16 + fo4];
            FMA4(acc, p, wv4)
        }
#pragma unroll 8
        for (int g = 0; g < 32; ++g) {
            float p = aggS[ln*128 + t*32 + g];
            float4 wv4 = *(const float4*)&Weff1[(t*40 + 8 + g)*16 + fo4];
            FMA4(acc, p, wv4)
        }
        *(float4*)&postS[ln*64 + t*16 + fo4] = acc;
    }
    __syncthreads();
    {   // mixing linear
        int ln = tid >> 4, q = tid & 15;
        int c4 = q*4;
        float4 acc = *(const float4*)&blin1[c4];
#pragma unroll 8
        for (int o = 0; o < 64; ++o) {
            float p = postS[ln*64 + o];
            float4 wv4 = *(const float4*)&Wlin1[o*64 + c4];
            FMA4(acc, p, wv4)
        }
        *(float4*)&y1[(base+ln)*64 + c4] = acc;
    }
}

// ---------------------------------------------------------------- BN stats (sum, sumsq) via block partials + atomics
template<int C, int LOGC>
__global__ __launch_bounds__(256) void bn_stats_kernel(
    const float* __restrict__ y, float* __restrict__ sum, float* __restrict__ sq)
{
    __shared__ float sS[256], qS[256];
    const int tid = threadIdx.x;
    const int c  = tid & (C-1);
    const int rg = tid >> LOGC;
    const int G  = 256 >> LOGC;
    const int rowBase = blockIdx.x * 128;
    float s = 0.f, q = 0.f;
    for (int r = rg; r < 128; r += G) {
        float v = y[(rowBase + r)*C + c];
        s += v; q += v*v;
    }
    sS[tid] = s; qS[tid] = q;
    __syncthreads();
    if (rg == 0) {
        for (int g2 = 1; g2 < G; ++g2) { s += sS[g2*C + c]; q += qS[g2*C + c]; }
        atomicAdd(&sum[c], s); atomicAdd(&sq[c], q);
    }
}

// ---------------------------------------------------------------- BN1 apply + relu, in place on y1
__global__ __launch_bounds__(256) void bn1_apply_kernel(
    float* __restrict__ y, const float* __restrict__ sum, const float* __restrict__ sq,
    const float* __restrict__ gamma, const float* __restrict__ beta)
{
    const int idx4 = blockIdx.x*256 + threadIdx.x;   // over N*64/4
    float4 v = ((float4*)y)[idx4];
    const int c0 = (idx4 << 2) & 63;
    const float inv = 1.f/(float)NN;
    float sc[4], sh[4];
#pragma unroll
    for (int j = 0; j < 4; ++j) {
        int c = c0 + j;
        float mu  = sum[c]*inv;
        float var = sq[c]*inv - mu*mu;
        sc[j] = gamma[c]*rsqrtf(var + 1e-5f);
        sh[j] = beta[c] - mu*sc[j];
    }
    v.x = fmaxf(v.x*sc[0] + sh[0], 0.f);
    v.y = fmaxf(v.y*sc[1] + sh[1], 0.f);
    v.z = fmaxf(v.z*sc[2] + sh[2], 0.f);
    v.w = fmaxf(v.w*sc[3] + sh[3], 0.f);
    ((float4*)y)[idx4] = v;
}

// ---------------------------------------------------------------- layer2: u2,v2 [N,256] (register-tiled GEMM, K=64)
__global__ __launch_bounds__(256) void a2_kernel(
    const float* __restrict__ a1, const float* __restrict__ W2u, const float* __restrict__ W2v,
    const float* __restrict__ bpre2, float* __restrict__ u2, float* __restrict__ v2)
{
    __shared__ float4 As4[256];     // 16 nodes x 64 feats
    const int tid = threadIdx.x;
    As4[tid] = ((const float4*)a1)[blockIdx.x*256 + tid];
    __syncthreads();
    const int q = tid & 63, r = tid >> 6;
    const int nodeBase = blockIdx.x*16 + r*4;
    float4 accu[4], accv[4];
    const float4 bias = ((const float4*)bpre2)[q];
#pragma unroll
    for (int i = 0; i < 4; ++i) { accu[i] = bias; accv[i] = make_float4(0.f,0.f,0.f,0.f); }
    const float4* W2u4 = (const float4*)W2u;
    const float4* W2v4 = (const float4*)W2v;
#pragma unroll 4
    for (int kk = 0; kk < 16; ++kk) {
        float4 a4[4];
#pragma unroll
        for (int i = 0; i < 4; ++i) a4[i] = As4[(r*4+i)*16 + kk];
#pragma unroll
        for (int ks = 0; ks < 4; ++ks) {
            const int k = kk*4 + ks;
            const float4 wu4 = W2u4[k*64 + q];
            const float4 wv4 = W2v4[k*64 + q];
#pragma unroll
            for (int i = 0; i < 4; ++i) {
                const float av = (ks==0) ? a4[i].x : (ks==1) ? a4[i].y : (ks==2) ? a4[i].z : a4[i].w;
                FMA4(accu[i], av, wu4)
                FMA4(accv[i], av, wv4)
            }
        }
    }
#pragma unroll
    for (int i = 0; i < 4; ++i) {
        ((float4*)u2)[(nodeBase+i)*64 + q] = accu[i];
        ((float4*)v2)[(nodeBase+i)*64 + q] = accv[i];
    }
}

// ---------------------------------------------------------------- layer2 fused: agg + post + lin -> y2 [N,128]
__global__ __launch_bounds__(256) void b2_kernel(
    const int* __restrict__ nbr, const float* __restrict__ a1,
    const float* __restrict__ u2, const float* __restrict__ v2,
    const float* __restrict__ Weff2, const float* __restrict__ bpost2,
    const float* __restrict__ Wlin2, const float* __restrict__ blin2,
    float* __restrict__ y2)
{
    __shared__ int   nbrsS[8*7];
    __shared__ float a1S[8*64];
    __shared__ float aggS[8*1024];   // per node: [t][mean64,min64,max64,std64]
    __shared__ float postS[8*128];
    const int tid  = threadIdx.x;
    const int base = blockIdx.x * 8;
    if (tid < 56) nbrsS[tid] = nbr[base*7 + tid];
    a1S[tid]       = a1[base*64 + tid];
    a1S[tid + 256] = a1[base*64 + 256 + tid];
    __syncthreads();
    for (int ln = 0; ln < 8; ++ln) {
        const int tf = tid;
        float u = u2[(base+ln)*256 + tf];
        float s = 0.f, s2 = 0.f, mn = 3e38f, mx = -3e38f;
#pragma unroll
        for (int e = 0; e < 7; ++e) {
            float vv = v2[nbrsS[ln*7+e]*256 + tf];
            s += vv; s2 += vv*vv; mn = fminf(mn, vv); mx = fmaxf(mx, vv);
        }
        float mean = s * (1.f/7.f);
        float var  = s2 * (1.f/7.f) - mean*mean;
        float sd   = sqrtf(fmaxf(var, 0.f) + 1e-5f);
        int t = tf >> 6, f = tf & 63;
        int bo = ln*1024 + t*256 + f;
        aggS[bo]     = u + mean;
        aggS[bo+64]  = u + mn;
        aggS[bo+128] = u + mx;
        aggS[bo+192] = sd;
    }
    __syncthreads();
    {   // post-MLP: 8 nodes x 128 outputs, thread = (node, 4-col group)
        const int q = tid & 31, ln = tid >> 5;
        const int t = q >> 3, fo4 = (q & 7) * 4;
        float4 acc = *(const float4*)&bpost2[t*32 + fo4];
#pragma unroll 8
        for (int g = 0; g < 64; ++g) {
            float p = a1S[ln*64 + g];
            float4 wv4 = *(const float4*)&Weff2[(t*320 + g)*32 + fo4];
            FMA4(acc, p, wv4)
        }
#pragma unroll 8
        for (int g = 0; g < 256; ++g) {
            float p = aggS[ln*1024 + t*256 + g];
            float4 wv4 = *(const float4*)&Weff2[(t*320 + 64 + g)*32 + fo4];
            FMA4(acc, p, wv4)
        }
        *(float4*)&postS[ln*128 + t*32 + fo4] = acc;
    }
    __syncthreads();
    {   // mixing linear
        const int q = tid & 31, ln = tid >> 5;
        const int c4 = q*4;
        float4 acc = *(const float4*)&blin2[c4];
#pragma unroll 8
        for (int o = 0; o < 128; ++o) {
            float p = postS[ln*128 + o];
            float4 wv4 = *(const float4*)&Wlin2[o*128 + c4];
            FMA4(acc, p, wv4)
        }
        *(float4*)&y2[(base+ln)*128 + c4] = acc;
    }
}

// ---------------------------------------------------------------- BN2 + relu + per-graph mean pool -> out [128,128]
__global__ __launch_bounds__(128) void pool_kernel(
    const float* __restrict__ y2, const float* __restrict__ sum, const float* __restrict__ sq,
    const float* __restrict__ gamma, const float* __restrict__ beta, float* __restrict__ out)
{
    const int c = threadIdx.x;
    const int g = blockIdx.x;
    const float inv = 1.f/(float)NN;
    const float mu  = sum[c]*inv;
    const float var = sq[c]*inv - mu*mu;
    const float sc  = gamma[c]*rsqrtf(var + 1e-5f);
    const float sh  = beta[c] - mu*sc;
    float acc = 0.f;
    const int baseIdx = g*NPG*128 + c;
#pragma unroll 4
    for (int i = 0; i < NPG; ++i) {
        float v = y2[baseIdx + i*128];
        acc += fmaxf(v*sc + sh, 0.f);
    }
    out[g*128 + c] = acc * (1.f/(float)NPG);
}

// ---------------------------------------------------------------- launcher
extern "C" void kernel_launch(void* const* d_in, const int* in_sizes, int n_in,
                              void* d_out, int out_size, void* d_ws, size_t ws_size,
                              hipStream_t stream)
{
    const float* x      = (const float*)d_in[0];
    const float* pos    = (const float*)d_in[1];
    const float* Wpre1  = (const float*)d_in[2];
    const float* bpre1  = (const float*)d_in[3];
    const float* Wpost1 = (const float*)d_in[4];
    const float* bpost1 = (const float*)d_in[5];
    const float* Wlin1  = (const float*)d_in[6];
    const float* blin1  = (const float*)d_in[7];
    const float* bn1g   = (const float*)d_in[8];
    const float* bn1b   = (const float*)d_in[9];
    const float* Wpre2  = (const float*)d_in[10];
    const float* bpre2  = (const float*)d_in[11];
    const float* Wpost2 = (const float*)d_in[12];
    const float* bpost2 = (const float*)d_in[13];
    const float* Wlin2  = (const float*)d_in[14];
    const float* blin2  = (const float*)d_in[15];
    const float* bn2g   = (const float*)d_in[16];
    const float* bn2b   = (const float*)d_in[17];
    float* out = (float*)d_out;

    char* ws = (char*)d_ws;
    size_t off = 0;
    auto alloc = [&](size_t bytes) { void* p = ws + off; off += (bytes + 255) & ~(size_t)255; return p; };
    int*   nbr   = (int*)  alloc((size_t)NN*7*4);      //   1.8 MB
    float* u1    = (float*)alloc((size_t)NN*32*4);     //   8.4 MB
    float* v1    = (float*)alloc((size_t)NN*32*4);     //   8.4 MB
    float* y1    = (float*)alloc((size_t)NN*64*4);     //  16.8 MB (becomes a1 in place)
    float* u2    = (float*)alloc((size_t)NN*256*4);    //  67.1 MB
    float* v2    = (float*)alloc((size_t)NN*256*4);    //  67.1 MB
    float* y2    = (float*)alloc((size_t)NN*128*4);    //  33.6 MB
    float* Weff1 = (float*)alloc(2560*4);
    float* Weff2 = (float*)alloc(40960*4);
    float* W2u   = (float*)alloc(16384*4);
    float* W2v   = (float*)alloc(16384*4);
    float* stats = (float*)alloc(512*4);               // s1[64] q1[64] s2[128] q2[128]

    (void)hipMemsetAsync(stats, 0, 512*4, stream);
    prep_kernel<<<128, 256, 0, stream>>>(Wpost1, Wpost2, Wpre2, Weff1, Weff2, W2u, W2v);
    knn_kernel<<<NGRAPH, 512, 0, stream>>>(pos, nbr);
    a1_kernel<<<NN/8, 256, 0, stream>>>(x, Wpre1, bpre1, u1, v1);
    b1_kernel<<<NN/16, 256, 0, stream>>>(x, nbr, u1, v1, Weff1, bpost1, Wlin1, blin1, y1);
    bn_stats_kernel<64,6><<<NN/128, 256, 0, stream>>>(y1, stats, stats+64);
    bn1_apply_kernel<<<NN*64/4/256, 256, 0, stream>>>(y1, stats, stats+64, bn1g, bn1b);
    a2_kernel<<<NN/16, 256, 0, stream>>>(y1, W2u, W2v, bpre2, u2, v2);
    b2_kernel<<<NN/8, 256, 0, stream>>>(nbr, y1, u2, v2, Weff2, bpost2, Wlin2, blin2, y2);
    bn_stats_kernel<128,7><<<NN/128, 256, 0, stream>>>(y2, stats+128, stats+256);
    pool_kernel<<<NGRAPH, 128, 0, stream>>>(y2, stats+128, stats+256, bn2g, bn2b, out);
}

// Round 3
// 517.237 us; speedup vs baseline: 1.4493x; 1.4493x over previous
//
#include <hip/hip_runtime.h>
#include <math.h>

// PNANet on MI355X, round 3: kill b2's LDS bank conflicts + amortize weight loads
// via node-register-blocking (8 nodes/thread); fuse BN1-apply into a2/b2.
//
// Algebraic restructurings (unchanged):
//  * pre-MLP factorized: m[n,e] = u[n] + v[nbr[n,e]]
//  * degree==7 -> scalers folded into W_eff (post-MLP K: 832->320, 104->40)

#define NGRAPH 128
#define NPG    512
#define NN     (NGRAPH*NPG)   // 65536
#define KNB    7

constexpr double AVG_DEG_LOG_D = 2.0239670479173344;  // (100*ln6+200*ln7+700*ln8)/1000
constexpr double LOG8_D        = 2.0794415416798357;

#define FMA4(A_, P_, W_) { (A_).x += (P_)*(W_).x; (A_).y += (P_)*(W_).y; (A_).z += (P_)*(W_).z; (A_).w += (P_)*(W_).w; }

// ---------------------------------------------------------------- weight prep
__global__ __launch_bounds__(256) void prep_kernel(
    const float* __restrict__ Wpost1, const float* __restrict__ Wpost2,
    const float* __restrict__ Wpre2,
    float* __restrict__ Weff1, float* __restrict__ Weff2,
    float* __restrict__ W2u, float* __restrict__ W2v)
{
    const float AMP = (float)(LOG8_D / AVG_DEG_LOG_D);
    const float ATT = (float)(AVG_DEG_LOG_D / LOG8_D);
    for (int i = blockIdx.x*256 + threadIdx.x; i < 76288; i += gridDim.x*256) {
        if (i < 2560) {
            // Weff1 [4][40][16]; g<8 = x part, g>=8 = agg part (mean,min,max,std x8)
            int t = i / 640, r = i % 640, g = r >> 4, fo = r & 15;
            float val;
            if (g < 8) val = Wpost1[(t*104 + g)*16 + fo];
            else {
                int g2 = g - 8;
                val = Wpost1[(t*104 +  8 + g2)*16 + fo]
                    + AMP*Wpost1[(t*104 + 40 + g2)*16 + fo]
                    + ATT*Wpost1[(t*104 + 72 + g2)*16 + fo];
            }
            Weff1[i] = val;
        } else if (i < 43520) {
            // Weff2 [4][320][32]; g<64 = x part, g>=64 = agg part (mean,min,max,std x64)
            int j = i - 2560;
            int t = j / 10240, r = j % 10240, g = r >> 5, fo = r & 31;
            float val;
            if (g < 64) val = Wpost2[(t*832 + g)*32 + fo];
            else {
                int g2 = g - 64;
                val = Wpost2[(t*832 +  64 + g2)*32 + fo]
                    + AMP*Wpost2[(t*832 + 320 + g2)*32 + fo]
                    + ATT*Wpost2[(t*832 + 576 + g2)*32 + fo];
            }
            Weff2[j] = val;
        } else {
            // W2u/W2v: [k=64][tf=256]; u rows = W_pre2[t][k], v rows = W_pre2[t][64+k]
            int j = i - 43520;
            int half = j >> 14, j2 = j & 16383;
            int k = j2 >> 8, tf = j2 & 255, t = tf >> 6, f = tf & 63;
            if (half == 0) W2u[j2] = Wpre2[(t*128 +      k)*64 + f];
            else           W2v[j2] = Wpre2[(t*128 + 64 + k)*64 + f];
        }
    }
}

// ---------------------------------------------------------------- kNN (k=7) per graph
__global__ __launch_bounds__(512) void knn_kernel(const float* __restrict__ pos, int* __restrict__ nbr)
{
    __shared__ float4 posS[NPG];
    const int gb = blockIdx.x * NPG;
    {
        int j = threadIdx.x;
        posS[j] = make_float4(pos[(gb+j)*3+0], pos[(gb+j)*3+1], pos[(gb+j)*3+2], 0.f);
    }
    __syncthreads();
    const int i = threadIdx.x;
    const float4 pi = posS[i];
    float bd[KNB]; int bi[KNB];
#pragma unroll
    for (int e = 0; e < KNB; ++e) { bd[e] = 3.0e38f; bi[e] = -1; }
    for (int j = 0; j < NPG; ++j) {
        float4 pj = posS[j];
        float dx = pi.x - pj.x, dy = pi.y - pj.y, dz = pi.z - pj.z;
        float d2 = __fadd_rn(__fadd_rn(__fmul_rn(dx,dx), __fmul_rn(dy,dy)), __fmul_rn(dz,dz));
        if (j == i) d2 = __builtin_inff();
        bool cmp[KNB];
#pragma unroll
        for (int e = 0; e < KNB; ++e) cmp[e] = d2 < bd[e];
#pragma unroll
        for (int e = KNB-1; e >= 1; --e) {
            bd[e] = cmp[e-1] ? bd[e-1] : (cmp[e] ? d2 : bd[e]);
            bi[e] = cmp[e-1] ? bi[e-1] : (cmp[e] ? j  : bi[e]);
        }
        bd[0] = cmp[0] ? d2 : bd[0];
        bi[0] = cmp[0] ? j  : bi[0];
    }
#pragma unroll
    for (int e = 0; e < KNB; ++e) nbr[(gb+i)*KNB + e] = gb + bi[e];
}

// ---------------------------------------------------------------- layer1: u1,v1 [N,32]
__global__ __launch_bounds__(256) void a1_kernel(
    const float* __restrict__ x, const float* __restrict__ Wpre1, const float* __restrict__ bpre1,
    float* __restrict__ u1, float* __restrict__ v1)
{
    __shared__ float wS[512];
    __shared__ float bS[32];
    const int tid = threadIdx.x;
    wS[tid] = Wpre1[tid]; wS[tid+256] = Wpre1[tid+256];
    if (tid < 32) bS[tid] = bpre1[tid];
    __syncthreads();
    const int n  = blockIdx.x*8 + (tid>>5);
    const int tf = tid & 31;
    const int t = tf >> 3, f = tf & 7;
    float u = bS[tf], v = 0.f;
#pragma unroll
    for (int e = 0; e < 8; ++e) {
        float xv = x[n*8+e];
        u += xv * wS[(t*16 + e)*8 + f];
        v += xv * wS[(t*16 + 8 + e)*8 + f];
    }
    u1[n*32+tf] = u;
    v1[n*32+tf] = v;
}

// ---------------------------------------------------------------- layer1 fused: agg + post + lin -> y1 [N,64]
// aggS row stride 41 (bank = 9*row+g, conflict-free); postS stride 68
__global__ __launch_bounds__(256) void b1_kernel(
    const float* __restrict__ x, const int* __restrict__ nbr,
    const float* __restrict__ u1, const float* __restrict__ v1,
    const float* __restrict__ Weff1, const float* __restrict__ bpost1,
    const float* __restrict__ Wlin1, const float* __restrict__ blin1,
    float* __restrict__ y1)
{
    __shared__ int   nbrsS[16*7];
    __shared__ float xsS[16*8];
    __shared__ float aggS[64*41];    // row = ln*4+t, cols: mean8,min8,max8,std8
    __shared__ float postS[16*68];
    const int tid  = threadIdx.x;
    const int base = blockIdx.x * 16;
    if (tid < 112) nbrsS[tid] = nbr[base*7 + tid];
    if (tid < 128) xsS[tid]   = x[base*8 + tid];
    __syncthreads();
#pragma unroll
    for (int it = 0; it < 2; ++it) {
        int task = tid + 256*it;
        int ln = task >> 5, tf = task & 31;
        float u = u1[(base+ln)*32 + tf];
        float s = 0.f, s2 = 0.f, mn = 3e38f, mx = -3e38f;
#pragma unroll
        for (int e = 0; e < 7; ++e) {
            float vv = v1[nbrsS[ln*7+e]*32 + tf];
            s += vv; s2 += vv*vv; mn = fminf(mn, vv); mx = fmaxf(mx, vv);
        }
        float mean = s * (1.f/7.f);
        float var  = s2 * (1.f/7.f) - mean*mean;
        float sd   = sqrtf(fmaxf(var, 0.f) + 1e-5f);
        int t = tf >> 3, f = tf & 7;
        int bo = (ln*4 + t)*41 + f;
        aggS[bo]    = u + mean;
        aggS[bo+8]  = u + mn;
        aggS[bo+16] = u + mx;
        aggS[bo+24] = sd;
    }
    __syncthreads();
    {   // post-MLP: 16 nodes x 64 outputs, thread = (node, 4-col group)
        int ln = tid >> 4, q = tid & 15;
        int t = q >> 2, fo4 = (q & 3) * 4;
        float4 acc = *(const float4*)&bpost1[t*16 + fo4];
#pragma unroll
        for (int g = 0; g < 8; ++g) {
            float p = xsS[ln*8+g];
            float4 wv4 = *(const float4*)&Weff1[(t*40 + g)*16 + fo4];
            FMA4(acc, p, wv4)
        }
#pragma unroll 8
        for (int g = 0; g < 32; ++g) {
            float p = aggS[(ln*4 + t)*41 + g];
            float4 wv4 = *(const float4*)&Weff1[(t*40 + 8 + g)*16 + fo4];
            FMA4(acc, p, wv4)
        }
        *(float4*)&postS[ln*68 + t*16 + fo4] = acc;
    }
    __syncthreads();
    {   // mixing linear
        int ln = tid >> 4, q = tid & 15;
        int c4 = q*4;
        float4 acc = *(const float4*)&blin1[c4];
#pragma unroll 8
        for (int o = 0; o < 64; ++o) {
            float p = postS[ln*68 + o];
            float4 wv4 = *(const float4*)&Wlin1[o*64 + c4];
            FMA4(acc, p, wv4)
        }
        *(float4*)&y1[(base+ln)*64 + c4] = acc;
    }
}

// ---------------------------------------------------------------- BN stats (sum, sumsq)
template<int C, int LOGC>
__global__ __launch_bounds__(256) void bn_stats_kernel(
    const float* __restrict__ y, float* __restrict__ sum, float* __restrict__ sq)
{
    __shared__ float sS[256], qS[256];
    const int tid = threadIdx.x;
    const int c  = tid & (C-1);
    const int rg = tid >> LOGC;
    const int G  = 256 >> LOGC;
    const int rowBase = blockIdx.x * 128;
    float s = 0.f, q = 0.f;
    for (int r = rg; r < 128; r += G) {
        float v = y[(rowBase + r)*C + c];
        s += v; q += v*v;
    }
    sS[tid] = s; qS[tid] = q;
    __syncthreads();
    if (rg == 0) {
        for (int g2 = 1; g2 < G; ++g2) { s += sS[g2*C + c]; q += qS[g2*C + c]; }
        atomicAdd(&sum[c], s); atomicAdd(&sq[c], q);
    }
}

// ---------------------------------------------------------------- layer2 pre: u2,v2 [N,256]; BN1+relu fused on load
__global__ __launch_bounds__(256) void a2_kernel(
    const float* __restrict__ y1raw, const float* __restrict__ stats,
    const float* __restrict__ bn1g, const float* __restrict__ bn1b,
    const float* __restrict__ W2u, const float* __restrict__ W2v,
    const float* __restrict__ bpre2,
    float* __restrict__ u2, float* __restrict__ v2)
{
    __shared__ float4 As4[512];     // 32 nodes x 16 float4
    const int tid = threadIdx.x;
    const float inv = 1.f/(float)NN;
    for (int i = tid; i < 512; i += 256) {
        float4 vv = ((const float4*)y1raw)[blockIdx.x*512 + i];
        int c0 = (i & 15) * 4;
        float comp[4] = {vv.x, vv.y, vv.z, vv.w};
#pragma unroll
        for (int j = 0; j < 4; ++j) {
            int c = c0 + j;
            float mu  = stats[c]*inv;
            float var = stats[64+c]*inv - mu*mu;
            float sc  = bn1g[c]*rsqrtf(var + 1e-5f);
            float sh  = bn1b[c] - mu*sc;
            comp[j] = fmaxf(comp[j]*sc + sh, 0.f);
        }
        As4[i] = make_float4(comp[0], comp[1], comp[2], comp[3]);
    }
    __syncthreads();
    const int q = tid & 63, r = tid >> 6;
    const int nodeBase = blockIdx.x*32 + r*8;
    float4 accu[8], accv[8];
    const float4 bias = ((const float4*)bpre2)[q];
#pragma unroll
    for (int i = 0; i < 8; ++i) { accu[i] = bias; accv[i] = make_float4(0.f,0.f,0.f,0.f); }
    const float4* W2u4 = (const float4*)W2u;
    const float4* W2v4 = (const float4*)W2v;
#pragma unroll 2
    for (int kk = 0; kk < 16; ++kk) {
        float4 a4[8];
#pragma unroll
        for (int i = 0; i < 8; ++i) a4[i] = As4[(r*8+i)*16 + kk];
#pragma unroll
        for (int ks = 0; ks < 4; ++ks) {
            const int k = kk*4 + ks;
            const float4 wu4 = W2u4[k*64 + q];
            const float4 wv4 = W2v4[k*64 + q];
#pragma unroll
            for (int i = 0; i < 8; ++i) {
                const float av = (ks==0) ? a4[i].x : (ks==1) ? a4[i].y : (ks==2) ? a4[i].z : a4[i].w;
                FMA4(accu[i], av, wu4)
                FMA4(accv[i], av, wv4)
            }
        }
    }
#pragma unroll
    for (int i = 0; i < 8; ++i) {
        ((float4*)u2)[(nodeBase+i)*64 + q] = accu[i];
        ((float4*)v2)[(nodeBase+i)*64 + q] = accv[i];
    }
}

// ---------------------------------------------------------------- b2 helper: reduce acc[8] over h (8 chunks) via LDS tree
__device__ __forceinline__ void tree_reduce8(float4* acc, float4* redS, int h, int q)
{
#pragma unroll
    for (int step = 4; step >= 1; step >>= 1) {
        if (h >= step && h < 2*step) {
            const int s = h - step;
#pragma unroll
            for (int nn = 0; nn < 8; ++nn) redS[(s*8 + nn)*33 + q] = acc[nn];
        }
        __syncthreads();
        if (h < step) {
#pragma unroll
            for (int nn = 0; nn < 8; ++nn) {
                float4 r = redS[(h*8 + nn)*33 + q];
                acc[nn].x += r.x; acc[nn].y += r.y; acc[nn].z += r.z; acc[nn].w += r.w;
            }
        }
        __syncthreads();
    }
}

// ---------------------------------------------------------------- layer2 fused: agg + post + lin -> y2 [N,128]
// thread = (column q in [0,32), K-chunk h in [0,8)); 8 nodes per thread (weights read ONCE per block)
__global__ __launch_bounds__(256) void b2_kernel(
    const int* __restrict__ nbr, const float* __restrict__ y1raw,
    const float* __restrict__ stats, const float* __restrict__ bn1g, const float* __restrict__ bn1b,
    const float* __restrict__ u2, const float* __restrict__ v2,
    const float* __restrict__ Weff2, const float* __restrict__ bpost2,
    const float* __restrict__ Wlin2, const float* __restrict__ blin2,
    float* __restrict__ y2)
{
    __shared__ int   nbrsS[56];
    __shared__ float a1S[512];       // 8 nodes x 64 (post-BN activations)
    __shared__ float aggS[8224];     // rows (node*4+t), stride 257 | aliased as redS float4[<=1055]
    __shared__ float postS[8*132];
    float4* redS = (float4*)aggS;

    const int tid  = threadIdx.x;
    const int base = blockIdx.x * 8;
    if (tid < 56) nbrsS[tid] = nbr[base*7 + tid];
    {   // a1 = relu(bn1(y1raw))
        const float inv = 1.f/(float)NN;
        for (int i = tid; i < 512; i += 256) {
            int c = i & 63;
            float mu  = stats[c]*inv;
            float var = stats[64+c]*inv - mu*mu;
            float sc  = bn1g[c]*rsqrtf(var + 1e-5f);
            float sh  = bn1b[c] - mu*sc;
            a1S[i] = fmaxf(y1raw[base*64 + i]*sc + sh, 0.f);
        }
    }
    __syncthreads();
    // ---- aggregation: per node, 7-neighbor mean/min/max/std over 256 feats
    for (int ln = 0; ln < 8; ++ln) {
        float u = u2[(base+ln)*256 + tid];
        float s = 0.f, s2 = 0.f, mn = 3e38f, mx = -3e38f;
#pragma unroll
        for (int e = 0; e < 7; ++e) {
            float vv = v2[nbrsS[ln*7+e]*256 + tid];
            s += vv; s2 += vv*vv; mn = fminf(mn, vv); mx = fmaxf(mx, vv);
        }
        float mean = s * (1.f/7.f);
        float var  = s2 * (1.f/7.f) - mean*mean;
        float sd   = sqrtf(fmaxf(var, 0.f) + 1e-5f);
        const int t = tid >> 6, f = tid & 63;
        const int ro = (ln*4 + t)*257;
        aggS[ro +       f] = u + mean;
        aggS[ro +  64 + f] = u + mn;
        aggS[ro + 128 + f] = u + mx;
        aggS[ro + 192 + f] = sd;
    }
    __syncthreads();
    const int q = tid & 31, h = tid >> 5;
    const int t = q >> 3, c4 = q * 4;       // output column = t*32+(q&7)*4 = 4q
    // ---- post-MLP: K=320 per tower, chunk h covers G in [40h, 40h+40)
    float4 acc[8];
#pragma unroll
    for (int i = 0; i < 8; ++i) acc[i] = make_float4(0.f,0.f,0.f,0.f);
    {
        const int G0 = h*40;
#pragma unroll 4
        for (int gi = 0; gi < 40; ++gi) {
            const int G = G0 + gi;
            const float4 w4 = *(const float4*)&Weff2[(t*320 + G)*32 + (q&7)*4];
            const float* src; int stride;
            if (G < 64) { src = a1S + G;                stride = 64;   }
            else        { src = aggS + t*257 + (G-64);  stride = 1028; }
#pragma unroll
            for (int nn = 0; nn < 8; ++nn) { float p = src[nn*stride]; FMA4(acc[nn], p, w4) }
        }
    }
    __syncthreads();                 // aggS reads done; safe to reuse as redS
    tree_reduce8(acc, redS, h, q);
    if (h == 0) {
        float4 bb = *(const float4*)&bpost2[c4];
#pragma unroll
        for (int nn = 0; nn < 8; ++nn) {
            float4 a = acc[nn];
            a.x += bb.x; a.y += bb.y; a.z += bb.z; a.w += bb.w;
            *(float4*)&postS[nn*132 + c4] = a;
        }
    }
    __syncthreads();
    // ---- mixing linear: K=128, chunk h covers o in [16h, 16h+16)
    float4 acc2[8];
#pragma unroll
    for (int i = 0; i < 8; ++i) acc2[i] = make_float4(0.f,0.f,0.f,0.f);
    {
        const int o0 = h*16;
#pragma unroll 4
        for (int oi = 0; oi < 16; ++oi) {
            const int o = o0 + oi;
            const float4 w4 = *(const float4*)&Wlin2[o*128 + c4];
#pragma unroll
            for (int nn = 0; nn < 8; ++nn) { float p = postS[nn*132 + o]; FMA4(acc2[nn], p, w4) }
        }
    }
    tree_reduce8(acc2, redS, h, q);
    if (h == 0) {
        float4 bb = *(const float4*)&blin2[c4];
#pragma unroll
        for (int nn = 0; nn < 8; ++nn) {
            float4 a = acc2[nn];
            a.x += bb.x; a.y += bb.y; a.z += bb.z; a.w += bb.w;
            *(float4*)&y2[(base+nn)*128 + c4] = a;
        }
    }
}

// ---------------------------------------------------------------- BN2 + relu + per-graph mean pool -> out [128,128]
__global__ __launch_bounds__(128) void pool_kernel(
    const float* __restrict__ y2, const float* __restrict__ sum, const float* __restrict__ sq,
    const float* __restrict__ gamma, const float* __restrict__ beta, float* __restrict__ out)
{
    const int c = threadIdx.x;
    const int g = blockIdx.x;
    const float inv = 1.f/(float)NN;
    const float mu  = sum[c]*inv;
    const float var = sq[c]*inv - mu*mu;
    const float sc  = gamma[c]*rsqrtf(var + 1e-5f);
    const float sh  = beta[c] - mu*sc;
    float acc = 0.f;
    const int baseIdx = g*NPG*128 + c;
#pragma unroll 4
    for (int i = 0; i < NPG; ++i) {
        float v = y2[baseIdx + i*128];
        acc += fmaxf(v*sc + sh, 0.f);
    }
    out[g*128 + c] = acc * (1.f/(float)NPG);
}

// ---------------------------------------------------------------- launcher
extern "C" void kernel_launch(void* const* d_in, const int* in_sizes, int n_in,
                              void* d_out, int out_size, void* d_ws, size_t ws_size,
                              hipStream_t stream)
{
    const float* x      = (const float*)d_in[0];
    const float* pos    = (const float*)d_in[1];
    const float* Wpre1  = (const float*)d_in[2];
    const float* bpre1  = (const float*)d_in[3];
    const float* Wpost1 = (const float*)d_in[4];
    const float* bpost1 = (const float*)d_in[5];
    const float* Wlin1  = (const float*)d_in[6];
    const float* blin1  = (const float*)d_in[7];
    const float* bn1g   = (const float*)d_in[8];
    const float* bn1b   = (const float*)d_in[9];
    const float* Wpre2  = (const float*)d_in[10];
    const float* bpre2  = (const float*)d_in[11];
    const float* Wpost2 = (const float*)d_in[12];
    const float* bpost2 = (const float*)d_in[13];
    const float* Wlin2  = (const float*)d_in[14];
    const float* blin2  = (const float*)d_in[15];
    const float* bn2g   = (const float*)d_in[16];
    const float* bn2b   = (const float*)d_in[17];
    float* out = (float*)d_out;

    char* ws = (char*)d_ws;
    size_t off = 0;
    auto alloc = [&](size_t bytes) { void* p = ws + off; off += (bytes + 255) & ~(size_t)255; return p; };
    int*   nbr   = (int*)  alloc((size_t)NN*7*4);
    float* u1    = (float*)alloc((size_t)NN*32*4);
    float* v1    = (float*)alloc((size_t)NN*32*4);
    float* y1    = (float*)alloc((size_t)NN*64*4);     // raw (pre-BN)
    float* u2    = (float*)alloc((size_t)NN*256*4);
    float* v2    = (float*)alloc((size_t)NN*256*4);
    float* y2    = (float*)alloc((size_t)NN*128*4);    // raw (pre-BN)
    float* Weff1 = (float*)alloc(2560*4);
    float* Weff2 = (float*)alloc(40960*4);
    float* W2u   = (float*)alloc(16384*4);
    float* W2v   = (float*)alloc(16384*4);
    float* stats = (float*)alloc(512*4);               // s1[64] q1[64] s2[128] q2[128]

    (void)hipMemsetAsync(stats, 0, 512*4, stream);
    prep_kernel<<<128, 256, 0, stream>>>(Wpost1, Wpost2, Wpre2, Weff1, Weff2, W2u, W2v);
    knn_kernel<<<NGRAPH, 512, 0, stream>>>(pos, nbr);
    a1_kernel<<<NN/8, 256, 0, stream>>>(x, Wpre1, bpre1, u1, v1);
    b1_kernel<<<NN/16, 256, 0, stream>>>(x, nbr, u1, v1, Weff1, bpost1, Wlin1, blin1, y1);
    bn_stats_kernel<64,6><<<NN/128, 256, 0, stream>>>(y1, stats, stats+64);
    a2_kernel<<<NN/32, 256, 0, stream>>>(y1, stats, bn1g, bn1b, W2u, W2v, bpre2, u2, v2);
    b2_kernel<<<NN/8, 256, 0, stream>>>(nbr, y1, stats, bn1g, bn1b, u2, v2, Weff2, bpost2, Wlin2, blin2, y2);
    bn_stats_kernel<128,7><<<NN/128, 256, 0, stream>>>(y2, stats+128, stats+256);
    pool_kernel<<<NGRAPH, 128, 0, stream>>>(y2, stats+128, stats+256, bn2g, bn2b, out);
}

// Round 4
// 514.889 us; speedup vs baseline: 1.4559x; 1.0046x over previous
//
#include <hip/hip_runtime.h>
#include <math.h>

// PNANet on MI355X, round 4:
//  * b2: unified per-(node,tower) activation rows [a1|mean|min|max|std] pitch 328
//    -> branch-free inner loop, immediate-offset LDS reads (kills ~65% VALU overhead)
//  * bn_stats: 128 blocks (atomic contention 512->128 per address)
//  * knn: 2 blocks/graph -> all 256 CUs busy

#define NGRAPH 128
#define NPG    512
#define NN     (NGRAPH*NPG)   // 65536
#define KNB    7

constexpr double AVG_DEG_LOG_D = 2.0239670479173344;  // (100*ln6+200*ln7+700*ln8)/1000
constexpr double LOG8_D        = 2.0794415416798357;

#define FMA4(A_, P_, W_) { (A_).x += (P_)*(W_).x; (A_).y += (P_)*(W_).y; (A_).z += (P_)*(W_).z; (A_).w += (P_)*(W_).w; }

// ---------------------------------------------------------------- weight prep
__global__ __launch_bounds__(256) void prep_kernel(
    const float* __restrict__ Wpost1, const float* __restrict__ Wpost2,
    const float* __restrict__ Wpre2,
    float* __restrict__ Weff1, float* __restrict__ Weff2,
    float* __restrict__ W2u, float* __restrict__ W2v)
{
    const float AMP = (float)(LOG8_D / AVG_DEG_LOG_D);
    const float ATT = (float)(AVG_DEG_LOG_D / LOG8_D);
    for (int i = blockIdx.x*256 + threadIdx.x; i < 76288; i += gridDim.x*256) {
        if (i < 2560) {
            // Weff1 [4][40][16]; g<8 = x part, g>=8 = agg part (mean,min,max,std x8)
            int t = i / 640, r = i % 640, g = r >> 4, fo = r & 15;
            float val;
            if (g < 8) val = Wpost1[(t*104 + g)*16 + fo];
            else {
                int g2 = g - 8;
                val = Wpost1[(t*104 +  8 + g2)*16 + fo]
                    + AMP*Wpost1[(t*104 + 40 + g2)*16 + fo]
                    + ATT*Wpost1[(t*104 + 72 + g2)*16 + fo];
            }
            Weff1[i] = val;
        } else if (i < 43520) {
            // Weff2 [4][320][32]; g<64 = x part, g>=64 = agg part (mean,min,max,std x64)
            int j = i - 2560;
            int t = j / 10240, r = j % 10240, g = r >> 5, fo = r & 31;
            float val;
            if (g < 64) val = Wpost2[(t*832 + g)*32 + fo];
            else {
                int g2 = g - 64;
                val = Wpost2[(t*832 +  64 + g2)*32 + fo]
                    + AMP*Wpost2[(t*832 + 320 + g2)*32 + fo]
                    + ATT*Wpost2[(t*832 + 576 + g2)*32 + fo];
            }
            Weff2[j] = val;
        } else {
            // W2u/W2v: [k=64][tf=256]; u rows = W_pre2[t][k], v rows = W_pre2[t][64+k]
            int j = i - 43520;
            int half = j >> 14, j2 = j & 16383;
            int k = j2 >> 8, tf = j2 & 255, t = tf >> 6, f = tf & 63;
            if (half == 0) W2u[j2] = Wpre2[(t*128 +      k)*64 + f];
            else           W2v[j2] = Wpre2[(t*128 + 64 + k)*64 + f];
        }
    }
}

// ---------------------------------------------------------------- kNN (k=7); 2 blocks per graph
__global__ __launch_bounds__(256) void knn_kernel(const float* __restrict__ pos, int* __restrict__ nbr)
{
    __shared__ float4 posS[NPG];
    const int g    = blockIdx.x >> 1;
    const int half = blockIdx.x & 1;
    const int gb   = g * NPG;
    for (int j = threadIdx.x; j < NPG; j += 256)
        posS[j] = make_float4(pos[(gb+j)*3+0], pos[(gb+j)*3+1], pos[(gb+j)*3+2], 0.f);
    __syncthreads();
    const int i = half*256 + threadIdx.x;
    const float4 pi = posS[i];
    float bd[KNB]; int bi[KNB];
#pragma unroll
    for (int e = 0; e < KNB; ++e) { bd[e] = 3.0e38f; bi[e] = -1; }
    for (int j = 0; j < NPG; ++j) {
        float4 pj = posS[j];
        float dx = pi.x - pj.x, dy = pi.y - pj.y, dz = pi.z - pj.z;
        float d2 = __fadd_rn(__fadd_rn(__fmul_rn(dx,dx), __fmul_rn(dy,dy)), __fmul_rn(dz,dz));
        if (j == i) d2 = __builtin_inff();
        bool cmp[KNB];
#pragma unroll
        for (int e = 0; e < KNB; ++e) cmp[e] = d2 < bd[e];
#pragma unroll
        for (int e = KNB-1; e >= 1; --e) {
            bd[e] = cmp[e-1] ? bd[e-1] : (cmp[e] ? d2 : bd[e]);
            bi[e] = cmp[e-1] ? bi[e-1] : (cmp[e] ? j  : bi[e]);
        }
        bd[0] = cmp[0] ? d2 : bd[0];
        bi[0] = cmp[0] ? j  : bi[0];
    }
#pragma unroll
    for (int e = 0; e < KNB; ++e) nbr[(gb+i)*KNB + e] = gb + bi[e];
}

// ---------------------------------------------------------------- layer1: u1,v1 [N,32]
__global__ __launch_bounds__(256) void a1_kernel(
    const float* __restrict__ x, const float* __restrict__ Wpre1, const float* __restrict__ bpre1,
    float* __restrict__ u1, float* __restrict__ v1)
{
    __shared__ float wS[512];
    __shared__ float bS[32];
    const int tid = threadIdx.x;
    wS[tid] = Wpre1[tid]; wS[tid+256] = Wpre1[tid+256];
    if (tid < 32) bS[tid] = bpre1[tid];
    __syncthreads();
    const int n  = blockIdx.x*8 + (tid>>5);
    const int tf = tid & 31;
    const int t = tf >> 3, f = tf & 7;
    float u = bS[tf], v = 0.f;
#pragma unroll
    for (int e = 0; e < 8; ++e) {
        float xv = x[n*8+e];
        u += xv * wS[(t*16 + e)*8 + f];
        v += xv * wS[(t*16 + 8 + e)*8 + f];
    }
    u1[n*32+tf] = u;
    v1[n*32+tf] = v;
}

// ---------------------------------------------------------------- layer1 fused: agg + post + lin -> y1 [N,64]
__global__ __launch_bounds__(256) void b1_kernel(
    const float* __restrict__ x, const int* __restrict__ nbr,
    const float* __restrict__ u1, const float* __restrict__ v1,
    const float* __restrict__ Weff1, const float* __restrict__ bpost1,
    const float* __restrict__ Wlin1, const float* __restrict__ blin1,
    float* __restrict__ y1)
{
    __shared__ int   nbrsS[16*7];
    __shared__ float xsS[16*8];
    __shared__ float aggS[64*41];    // row = ln*4+t, cols: mean8,min8,max8,std8
    __shared__ float postS[16*68];
    const int tid  = threadIdx.x;
    const int base = blockIdx.x * 16;
    if (tid < 112) nbrsS[tid] = nbr[base*7 + tid];
    if (tid < 128) xsS[tid]   = x[base*8 + tid];
    __syncthreads();
#pragma unroll
    for (int it = 0; it < 2; ++it) {
        int task = tid + 256*it;
        int ln = task >> 5, tf = task & 31;
        float u = u1[(base+ln)*32 + tf];
        float s = 0.f, s2 = 0.f, mn = 3e38f, mx = -3e38f;
#pragma unroll
        for (int e = 0; e < 7; ++e) {
            float vv = v1[nbrsS[ln*7+e]*32 + tf];
            s += vv; s2 += vv*vv; mn = fminf(mn, vv); mx = fmaxf(mx, vv);
        }
        float mean = s * (1.f/7.f);
        float var  = s2 * (1.f/7.f) - mean*mean;
        float sd   = sqrtf(fmaxf(var, 0.f) + 1e-5f);
        int t = tf >> 3, f = tf & 7;
        int bo = (ln*4 + t)*41 + f;
        aggS[bo]    = u + mean;
        aggS[bo+8]  = u + mn;
        aggS[bo+16] = u + mx;
        aggS[bo+24] = sd;
    }
    __syncthreads();
    {   // post-MLP: 16 nodes x 64 outputs
        int ln = tid >> 4, q = tid & 15;
        int t = q >> 2, fo4 = (q & 3) * 4;
        float4 acc = *(const float4*)&bpost1[t*16 + fo4];
#pragma unroll
        for (int g = 0; g < 8; ++g) {
            float p = xsS[ln*8+g];
            float4 wv4 = *(const float4*)&Weff1[(t*40 + g)*16 + fo4];
            FMA4(acc, p, wv4)
        }
#pragma unroll 8
        for (int g = 0; g < 32; ++g) {
            float p = aggS[(ln*4 + t)*41 + g];
            float4 wv4 = *(const float4*)&Weff1[(t*40 + 8 + g)*16 + fo4];
            FMA4(acc, p, wv4)
        }
        *(float4*)&postS[ln*68 + t*16 + fo4] = acc;
    }
    __syncthreads();
    {   // mixing linear
        int ln = tid >> 4, q = tid & 15;
        int c4 = q*4;
        float4 acc = *(const float4*)&blin1[c4];
#pragma unroll 8
        for (int o = 0; o < 64; ++o) {
            float p = postS[ln*68 + o];
            float4 wv4 = *(const float4*)&Wlin1[o*64 + c4];
            FMA4(acc, p, wv4)
        }
        *(float4*)&y1[(base+ln)*64 + c4] = acc;
    }
}

// ---------------------------------------------------------------- BN stats; 128 blocks, row loop
template<int C, int LOGC>
__global__ __launch_bounds__(256) void bn_stats_kernel(
    const float* __restrict__ y, float* __restrict__ sum, float* __restrict__ sq)
{
    __shared__ float sS[256], qS[256];
    const int tid = threadIdx.x;
    const int c  = tid & (C-1);
    const int rg = tid >> LOGC;
    const int G  = 256 >> LOGC;
    const int ROWS = NN/128;                 // 512 rows per block
    const int rowBase = blockIdx.x * ROWS;
    float s = 0.f, q = 0.f;
    for (int r = rg; r < ROWS; r += G) {
        float v = y[(rowBase + r)*C + c];
        s += v; q += v*v;
    }
    sS[tid] = s; qS[tid] = q;
    __syncthreads();
    if (rg == 0) {
        for (int g2 = 1; g2 < G; ++g2) { s += sS[g2*C + c]; q += qS[g2*C + c]; }
        atomicAdd(&sum[c], s); atomicAdd(&sq[c], q);
    }
}

// ---------------------------------------------------------------- layer2 pre: u2,v2 [N,256]; BN1+relu fused
__global__ __launch_bounds__(256) void a2_kernel(
    const float* __restrict__ y1raw, const float* __restrict__ stats,
    const float* __restrict__ bn1g, const float* __restrict__ bn1b,
    const float* __restrict__ W2u, const float* __restrict__ W2v,
    const float* __restrict__ bpre2,
    float* __restrict__ u2, float* __restrict__ v2)
{
    __shared__ float4 As4[512];     // 32 nodes x 16 float4
    const int tid = threadIdx.x;
    const float inv = 1.f/(float)NN;
    for (int i = tid; i < 512; i += 256) {
        float4 vv = ((const float4*)y1raw)[blockIdx.x*512 + i];
        int c0 = (i & 15) * 4;
        float comp[4] = {vv.x, vv.y, vv.z, vv.w};
#pragma unroll
        for (int j = 0; j < 4; ++j) {
            int c = c0 + j;
            float mu  = stats[c]*inv;
            float var = stats[64+c]*inv - mu*mu;
            float sc  = bn1g[c]*rsqrtf(var + 1e-5f);
            float sh  = bn1b[c] - mu*sc;
            comp[j] = fmaxf(comp[j]*sc + sh, 0.f);
        }
        As4[i] = make_float4(comp[0], comp[1], comp[2], comp[3]);
    }
    __syncthreads();
    const int q = tid & 63, r = tid >> 6;
    const int nodeBase = blockIdx.x*32 + r*8;
    float4 accu[8], accv[8];
    const float4 bias = ((const float4*)bpre2)[q];
#pragma unroll
    for (int i = 0; i < 8; ++i) { accu[i] = bias; accv[i] = make_float4(0.f,0.f,0.f,0.f); }
    const float4* W2u4 = (const float4*)W2u;
    const float4* W2v4 = (const float4*)W2v;
#pragma unroll 2
    for (int kk = 0; kk < 16; ++kk) {
        float4 a4[8];
#pragma unroll
        for (int i = 0; i < 8; ++i) a4[i] = As4[(r*8+i)*16 + kk];
#pragma unroll
        for (int ks = 0; ks < 4; ++ks) {
            const int k = kk*4 + ks;
            const float4 wu4 = W2u4[k*64 + q];
            const float4 wv4 = W2v4[k*64 + q];
#pragma unroll
            for (int i = 0; i < 8; ++i) {
                const float av = (ks==0) ? a4[i].x : (ks==1) ? a4[i].y : (ks==2) ? a4[i].z : a4[i].w;
                FMA4(accu[i], av, wu4)
                FMA4(accv[i], av, wv4)
            }
        }
    }
#pragma unroll
    for (int i = 0; i < 8; ++i) {
        ((float4*)u2)[(nodeBase+i)*64 + q] = accu[i];
        ((float4*)v2)[(nodeBase+i)*64 + q] = accv[i];
    }
}

// ---------------------------------------------------------------- b2 helper: reduce acc[8] over 8 K-chunks
__device__ __forceinline__ void tree_reduce8(float4* acc, float4* redS, int h, int q)
{
#pragma unroll
    for (int step = 4; step >= 1; step >>= 1) {
        if (h >= step && h < 2*step) {
            const int s = h - step;
#pragma unroll
            for (int nn = 0; nn < 8; ++nn) redS[(s*8 + nn)*33 + q] = acc[nn];
        }
        __syncthreads();
        if (h < step) {
#pragma unroll
            for (int nn = 0; nn < 8; ++nn) {
                float4 r = redS[(h*8 + nn)*33 + q];
                acc[nn].x += r.x; acc[nn].y += r.y; acc[nn].z += r.z; acc[nn].w += r.w;
            }
        }
        __syncthreads();
    }
}

// ---------------------------------------------------------------- layer2 fused: agg + post + lin -> y2 [N,128]
// Unified activation rows: actS[(node*4+t)*328 + G], G in [0,320) = [a1(64)|mean|min|max|std]
// -> post-MLP src index == Weff2 row index G, branch-free, immediate LDS offsets.
__global__ __launch_bounds__(256) void b2_kernel(
    const int* __restrict__ nbr, const float* __restrict__ y1raw,
    const float* __restrict__ stats, const float* __restrict__ bn1g, const float* __restrict__ bn1b,
    const float* __restrict__ u2, const float* __restrict__ v2,
    const float* __restrict__ Weff2, const float* __restrict__ bpost2,
    const float* __restrict__ Wlin2, const float* __restrict__ blin2,
    float* __restrict__ y2)
{
    __shared__ int   nbrsS[56];
    __shared__ float a1S[512];        // 8 nodes x 64 post-BN activations
    __shared__ float actS[32*328];    // 32 rows (node*4+t), pitch 328 (pad 8)
    __shared__ float postS[8*132];
    float4* redS = (float4*)actS;     // alias; used only when actS is dead

    const int tid  = threadIdx.x;
    const int base = blockIdx.x * 8;
    if (tid < 56) nbrsS[tid] = nbr[base*7 + tid];
    {   // a1 = relu(bn1(y1raw))
        const float inv = 1.f/(float)NN;
        for (int i = tid; i < 512; i += 256) {
            int c = i & 63;
            float mu  = stats[c]*inv;
            float var = stats[64+c]*inv - mu*mu;
            float sc  = bn1g[c]*rsqrtf(var + 1e-5f);
            float sh  = bn1b[c] - mu*sc;
            a1S[i] = fmaxf(y1raw[base*64 + i]*sc + sh, 0.f);
        }
    }
    __syncthreads();
    // ---- build unified activation rows: a1 copy (x4 towers) + 7-neighbor agg
    {
        const int t = tid >> 6, f = tid & 63;
        for (int ln = 0; ln < 8; ++ln) {
            actS[(ln*4 + t)*328 + f] = a1S[ln*64 + f];   // a1 replicated per tower
            float u = u2[(base+ln)*256 + tid];
            float s = 0.f, s2 = 0.f, mn = 3e38f, mx = -3e38f;
#pragma unroll
            for (int e = 0; e < 7; ++e) {
                float vv = v2[nbrsS[ln*7+e]*256 + tid];
                s += vv; s2 += vv*vv; mn = fminf(mn, vv); mx = fmaxf(mx, vv);
            }
            float mean = s * (1.f/7.f);
            float var  = s2 * (1.f/7.f) - mean*mean;
            float sd   = sqrtf(fmaxf(var, 0.f) + 1e-5f);
            const int ro = (ln*4 + t)*328 + 64 + f;
            actS[ro      ] = u + mean;
            actS[ro +  64] = u + mn;
            actS[ro + 128] = u + mx;
            actS[ro + 192] = sd;
        }
    }
    __syncthreads();
    const int q = tid & 31, h = tid >> 5;
    const int t = q >> 3, c4 = q * 4;            // post output col = 4q = t*32+(q&7)*4
    // ---- post-MLP: K=320 per tower, chunk h covers G in [40h, 40h+40)
    float4 acc[8];
#pragma unroll
    for (int i = 0; i < 8; ++i) acc[i] = make_float4(0.f,0.f,0.f,0.f);
    {
        const float* wp = Weff2 + (t*320 + h*40)*32 + (q & 7)*4;
        const float* ap = actS + t*328 + h*40;
#pragma unroll 4
        for (int gi = 0; gi < 40; ++gi) {
            const float4 w4 = *(const float4*)wp; wp += 32;
#pragma unroll
            for (int nn = 0; nn < 8; ++nn) { float p = ap[nn*1312 + gi]; FMA4(acc[nn], p, w4) }
        }
    }
    __syncthreads();                 // actS reads done; safe to alias as redS
    tree_reduce8(acc, redS, h, q);
    if (h == 0) {
        float4 bb = *(const float4*)&bpost2[c4];
#pragma unroll
        for (int nn = 0; nn < 8; ++nn) {
            float4 a = acc[nn];
            a.x += bb.x; a.y += bb.y; a.z += bb.z; a.w += bb.w;
            *(float4*)&postS[nn*132 + c4] = a;
        }
    }
    __syncthreads();
    // ---- mixing linear: K=128, chunk h covers o in [16h, 16h+16)
    float4 acc2[8];
#pragma unroll
    for (int i = 0; i < 8; ++i) acc2[i] = make_float4(0.f,0.f,0.f,0.f);
    {
        const float* wp = Wlin2 + (h*16)*128 + c4;
        const float* pp = postS + h*16;
#pragma unroll 4
        for (int oi = 0; oi < 16; ++oi) {
            const float4 w4 = *(const float4*)wp; wp += 128;
#pragma unroll
            for (int nn = 0; nn < 8; ++nn) { float p = pp[nn*132 + oi]; FMA4(acc2[nn], p, w4) }
        }
    }
    tree_reduce8(acc2, redS, h, q);
    if (h == 0) {
        float4 bb = *(const float4*)&blin2[c4];
#pragma unroll
        for (int nn = 0; nn < 8; ++nn) {
            float4 a = acc2[nn];
            a.x += bb.x; a.y += bb.y; a.z += bb.z; a.w += bb.w;
            *(float4*)&y2[(base+nn)*128 + c4] = a;
        }
    }
}

// ---------------------------------------------------------------- BN2 + relu + per-graph mean pool -> out [128,128]
__global__ __launch_bounds__(128) void pool_kernel(
    const float* __restrict__ y2, const float* __restrict__ sum, const float* __restrict__ sq,
    const float* __restrict__ gamma, const float* __restrict__ beta, float* __restrict__ out)
{
    const int c = threadIdx.x;
    const int g = blockIdx.x;
    const float inv = 1.f/(float)NN;
    const float mu  = sum[c]*inv;
    const float var = sq[c]*inv - mu*mu;
    const float sc  = gamma[c]*rsqrtf(var + 1e-5f);
    const float sh  = beta[c] - mu*sc;
    float acc = 0.f;
    const int baseIdx = g*NPG*128 + c;
#pragma unroll 4
    for (int i = 0; i < NPG; ++i) {
        float v = y2[baseIdx + i*128];
        acc += fmaxf(v*sc + sh, 0.f);
    }
    out[g*128 + c] = acc * (1.f/(float)NPG);
}

// ---------------------------------------------------------------- launcher
extern "C" void kernel_launch(void* const* d_in, const int* in_sizes, int n_in,
                              void* d_out, int out_size, void* d_ws, size_t ws_size,
                              hipStream_t stream)
{
    const float* x      = (const float*)d_in[0];
    const float* pos    = (const float*)d_in[1];
    const float* Wpre1  = (const float*)d_in[2];
    const float* bpre1  = (const float*)d_in[3];
    const float* Wpost1 = (const float*)d_in[4];
    const float* bpost1 = (const float*)d_in[5];
    const float* Wlin1  = (const float*)d_in[6];
    const float* blin1  = (const float*)d_in[7];
    const float* bn1g   = (const float*)d_in[8];
    const float* bn1b   = (const float*)d_in[9];
    const float* Wpre2  = (const float*)d_in[10];
    const float* bpre2  = (const float*)d_in[11];
    const float* Wpost2 = (const float*)d_in[12];
    const float* bpost2 = (const float*)d_in[13];
    const float* Wlin2  = (const float*)d_in[14];
    const float* blin2  = (const float*)d_in[15];
    const float* bn2g   = (const float*)d_in[16];
    const float* bn2b   = (const float*)d_in[17];
    float* out = (float*)d_out;

    char* ws = (char*)d_ws;
    size_t off = 0;
    auto alloc = [&](size_t bytes) { void* p = ws + off; off += (bytes + 255) & ~(size_t)255; return p; };
    int*   nbr   = (int*)  alloc((size_t)NN*7*4);
    float* u1    = (float*)alloc((size_t)NN*32*4);
    float* v1    = (float*)alloc((size_t)NN*32*4);
    float* y1    = (float*)alloc((size_t)NN*64*4);     // raw (pre-BN)
    float* u2    = (float*)alloc((size_t)NN*256*4);
    float* v2    = (float*)alloc((size_t)NN*256*4);
    float* y2    = (float*)alloc((size_t)NN*128*4);    // raw (pre-BN)
    float* Weff1 = (float*)alloc(2560*4);
    float* Weff2 = (float*)alloc(40960*4);
    float* W2u   = (float*)alloc(16384*4);
    float* W2v   = (float*)alloc(16384*4);
    float* stats = (float*)alloc(512*4);               // s1[64] q1[64] s2[128] q2[128]

    (void)hipMemsetAsync(stats, 0, 512*4, stream);
    prep_kernel<<<128, 256, 0, stream>>>(Wpost1, Wpost2, Wpre2, Weff1, Weff2, W2u, W2v);
    knn_kernel<<<NGRAPH*2, 256, 0, stream>>>(pos, nbr);
    a1_kernel<<<NN/8, 256, 0, stream>>>(x, Wpre1, bpre1, u1, v1);
    b1_kernel<<<NN/16, 256, 0, stream>>>(x, nbr, u1, v1, Weff1, bpost1, Wlin1, blin1, y1);
    bn_stats_kernel<64,6><<<128, 256, 0, stream>>>(y1, stats, stats+64);
    a2_kernel<<<NN/32, 256, 0, stream>>>(y1, stats, bn1g, bn1b, W2u, W2v, bpre2, u2, v2);
    b2_kernel<<<NN/8, 256, 0, stream>>>(nbr, y1, stats, bn1g, bn1b, u2, v2, Weff2, bpost2, Wlin2, blin2, y2);
    bn_stats_kernel<128,7><<<128, 256, 0, stream>>>(y2, stats+128, stats+256);
    pool_kernel<<<NGRAPH, 128, 0, stream>>>(y2, stats+128, stats+256, bn2g, bn2b, out);
}